// Round 3
// baseline (568.668 us; speedup 1.0000x reference)
//
#include <hip/hip_runtime.h>
#include <math.h>

#define N_BINS 15
#define LOG2E 1.44269504088896340736f

// DPP cross-lane XOR within a 16-lane row: masks {1,3,7,15} span the group.
// 0xB1 = quad_perm[1,0,3,2] (xor1), 0x1B = quad_perm[3,2,1,0] (xor3),
// 0x141 = ROW_HALF_MIRROR (xor7), 0x140 = ROW_MIRROR (xor15).
template <int CTRL>
__device__ __forceinline__ float dpp_xor(float x) {
    int xi = __builtin_bit_cast(int, x);
    int r  = __builtin_amdgcn_update_dpp(xi, xi, CTRL, 0xF, 0xF, false);
    return __builtin_bit_cast(float, r);
}

// 16 lanes per row (wave = 4 rows/iter). C==100 fast path: lane sl holds
// float4 #sl and #(16+sl) (masked to sl<9 -> elements 64..99, no OOB).
// accuracy = (logits[row][label] == rowmax)  -- no argmax index needed.
__global__ __launch_bounds__(256) void ece_main(const float* __restrict__ logits,
                                                const int* __restrict__ labels,
                                                float* __restrict__ ws,
                                                int N, int C) {
    __shared__ float s_bins[3][N_BINS];
    const int tid = threadIdx.x;
    if (tid < 3 * N_BINS) (&s_bins[0][0])[tid] = 0.f;
    __syncthreads();

    const int sl = tid & 15;
    const int group   = (blockIdx.x * blockDim.x + tid) >> 4;
    const int ngroups = (gridDim.x * blockDim.x) >> 4;

    if (C == 100) {
        const bool h = (sl < 9);
        for (int row = group; row < N; row += ngroups) {
            const float4* rp4 = (const float4*)(logits + (size_t)row * 100);
            float4 a = rp4[sl];
            float4 b;
            if (h) b = rp4[16 + sl];
            else   b = make_float4(-INFINITY, -INFINITY, -INFINITY, -INFINITY);

            // row max: 7-op local tree + 4-step DPP butterfly (no DS pipe)
            float m = fmaxf(fmaxf(fmaxf(a.x, a.y), fmaxf(a.z, a.w)),
                            fmaxf(fmaxf(b.x, b.y), fmaxf(b.z, b.w)));
            m = fmaxf(m, dpp_xor<0xB1>(m));
            m = fmaxf(m, dpp_xor<0x1B>(m));
            m = fmaxf(m, dpp_xor<0x141>(m));
            m = fmaxf(m, dpp_xor<0x140>(m));

            // sum exp(v - m) = sum exp2(v*log2e - m*log2e); -inf lanes give 0
            float t = -m * LOG2E;
            float s = exp2f(fmaf(a.x, LOG2E, t)) + exp2f(fmaf(a.y, LOG2E, t))
                    + exp2f(fmaf(a.z, LOG2E, t)) + exp2f(fmaf(a.w, LOG2E, t))
                    + exp2f(fmaf(b.x, LOG2E, t)) + exp2f(fmaf(b.y, LOG2E, t))
                    + exp2f(fmaf(b.z, LOG2E, t)) + exp2f(fmaf(b.w, LOG2E, t));
            s += dpp_xor<0xB1>(s);
            s += dpp_xor<0x1B>(s);
            s += dpp_xor<0x141>(s);
            s += dpp_xor<0x140>(s);

            if (sl == 0) {
                float conf = 1.0f / s;
                int bin = (int)ceilf(conf * (float)N_BINS) - 1;
                bin = min(max(bin, 0), N_BINS - 1);
                int lab = labels[row];                       // 4 lanes/wave, coalesced
                float vl = logits[(size_t)row * 100 + lab];  // L1 hit (row just read)
                atomicAdd(&s_bins[0][bin], 1.0f);
                atomicAdd(&s_bins[1][bin], conf);
                atomicAdd(&s_bins[2][bin], (vl == m) ? 1.0f : 0.0f);
            }
        }
    } else {
        // generic fallback (not hit for this problem's shape)
        for (int row = group; row < N; row += ngroups) {
            const float* rp = logits + (size_t)row * C;
            float m = -INFINITY; int mi = C;
            for (int j = sl; j < C; j += 16) {
                float v = rp[j];
                if (v > m) { m = v; mi = j; }
            }
            #pragma unroll
            for (int off = 1; off < 16; off <<= 1) {
                float om = __shfl_xor(m, off);
                int   oi = __shfl_xor(mi, off);
                if (om > m || (om == m && oi < mi)) { m = om; mi = oi; }
            }
            float s = 0.f;
            for (int j = sl; j < C; j += 16) s += __expf(rp[j] - m);
            #pragma unroll
            for (int off = 1; off < 16; off <<= 1) s += __shfl_xor(s, off);
            if (sl == 0) {
                float conf = 1.0f / s;
                int bin = (int)ceilf(conf * (float)N_BINS) - 1;
                bin = min(max(bin, 0), N_BINS - 1);
                float acc = (mi == labels[row]) ? 1.0f : 0.0f;
                atomicAdd(&s_bins[0][bin], 1.0f);
                atomicAdd(&s_bins[1][bin], conf);
                atomicAdd(&s_bins[2][bin], acc);
            }
        }
    }

    __syncthreads();
    if (tid < N_BINS) {
        atomicAdd(&ws[tid],              s_bins[0][tid]);
        atomicAdd(&ws[N_BINS + tid],     s_bins[1][tid]);
        atomicAdd(&ws[2 * N_BINS + tid], s_bins[2][tid]);
    }
}

__global__ void ece_final(const float* __restrict__ ws, float* __restrict__ out, float invN) {
    if (threadIdx.x == 0 && blockIdx.x == 0) {
        float ece = 0.f;
        for (int b = 0; b < N_BINS; ++b) {
            float c = ws[b];
            if (c > 0.f) {
                float conf_m = ws[N_BINS + b] / c;
                float acc_m  = ws[2 * N_BINS + b] / c;
                ece += fabsf(conf_m - acc_m) * (c * invN);
            }
        }
        out[0] = ece;
    }
}

extern "C" void kernel_launch(void* const* d_in, const int* in_sizes, int n_in,
                              void* d_out, int out_size, void* d_ws, size_t ws_size,
                              hipStream_t stream) {
    const float* logits = (const float*)d_in[0];
    const int*   labels = (const int*)d_in[1];
    const int N = in_sizes[1];
    const int C = in_sizes[0] / N;
    float* ws = (float*)d_ws;

    hipMemsetAsync(ws, 0, 3 * N_BINS * sizeof(float), stream);

    const int threads = 256;
    const int blocks = 2048;   // 8 blocks/CU, 32 waves/CU; 32768 row-groups
    ece_main<<<blocks, threads, 0, stream>>>(logits, labels, ws, N, C);
    ece_final<<<1, 64, 0, stream>>>(ws, (float*)d_out, 1.0f / (float)N);
}

// Round 4
// 549.031 us; speedup vs baseline: 1.0358x; 1.0358x over previous
//
#include <hip/hip_runtime.h>
#include <math.h>

#define N_BINS 15
#define LOG2E 1.44269504088896340736f

// DPP cross-lane XOR within a 16-lane group: masks {1,3,7,15} span the group.
// 0xB1=quad_perm[1,0,3,2](xor1) 0x1B=quad_perm[3,2,1,0](xor3)
// 0x141=ROW_HALF_MIRROR(xor7)   0x140=ROW_MIRROR(xor15)   [verified R3: absmax=0]
template <int CTRL>
__device__ __forceinline__ float dpp_xor(float x) {
    int xi = __builtin_bit_cast(int, x);
    int r  = __builtin_amdgcn_update_dpp(xi, xi, CTRL, 0xF, 0xF, false);
    return __builtin_bit_cast(float, r);
}

__device__ __forceinline__ float group_max(float m) {
    m = fmaxf(m, dpp_xor<0xB1>(m));
    m = fmaxf(m, dpp_xor<0x1B>(m));
    m = fmaxf(m, dpp_xor<0x141>(m));
    m = fmaxf(m, dpp_xor<0x140>(m));
    return m;
}
__device__ __forceinline__ float group_sum(float s) {
    s += dpp_xor<0xB1>(s);
    s += dpp_xor<0x1B>(s);
    s += dpp_xor<0x141>(s);
    s += dpp_xor<0x140>(s);
    return s;
}

// Per-row body given the row's 8 register elements + its label.
// acc = (owned element at index `lab` == rowmax), OR-reduced via ballot slice.
__device__ __forceinline__ void row_body(float4 a, float4 b, int lab, int sl,
                                         int group16, float* s_bins /*[3][N_BINS]*/) {
    float m = fmaxf(fmaxf(fmaxf(a.x, a.y), fmaxf(a.z, a.w)),
                    fmaxf(fmaxf(b.x, b.y), fmaxf(b.z, b.w)));
    m = group_max(m);

    float t = -m * LOG2E;
    float s = exp2f(fmaf(a.x, LOG2E, t)) + exp2f(fmaf(a.y, LOG2E, t))
            + exp2f(fmaf(a.z, LOG2E, t)) + exp2f(fmaf(a.w, LOG2E, t))
            + exp2f(fmaf(b.x, LOG2E, t)) + exp2f(fmaf(b.y, LOG2E, t))
            + exp2f(fmaf(b.z, LOG2E, t)) + exp2f(fmaf(b.w, LOG2E, t));
    s = group_sum(s);

    // which lane owns logits[lab]: q = lab>>2 owns float4 #q (a if q<16, b if q>=16)
    int q = lab >> 2, c = lab & 3;
    float pick = -INFINITY;
    if (q == sl)           pick = (c == 0 ? a.x : c == 1 ? a.y : c == 2 ? a.z : a.w);
    else if (q - 16 == sl) pick = (c == 0 ? b.x : c == 1 ? b.y : c == 2 ? b.z : b.w);
    unsigned long long mask = __ballot(pick == m);

    if (sl == 0) {
        float conf = 1.0f / s;
        int bin = (int)ceilf(conf * (float)N_BINS) - 1;
        bin = min(max(bin, 0), N_BINS - 1);
        float acc = ((mask >> (group16 * 16)) & 0xFFFFull) ? 1.0f : 0.0f;
        atomicAdd(&s_bins[bin], 1.0f);
        atomicAdd(&s_bins[N_BINS + bin], conf);
        atomicAdd(&s_bins[2 * N_BINS + bin], acc);
    }
}

// 16 lanes per row, 4 rows/wave, grid-stride unrolled x4 so 8 dwordx4 + 4
// label loads are in flight per wave-iteration (latency hiding; R3 showed
// VGPR=12 left the loop un-pipelined and memory-latency-bound).
__global__ __launch_bounds__(256, 4) void ece_main(const float* __restrict__ logits,
                                                   const int* __restrict__ labels,
                                                   float* __restrict__ ws,
                                                   int N, int C) {
    __shared__ float s_bins[3 * N_BINS];
    const int tid = threadIdx.x;
    if (tid < 3 * N_BINS) s_bins[tid] = 0.f;
    __syncthreads();

    const int sl = tid & 15;
    const int group16 = (tid >> 4) & 3;   // which 16-lane group within the wave
    const int group   = (blockIdx.x * blockDim.x + tid) >> 4;
    const int ngroups = (gridDim.x * blockDim.x) >> 4;

    if (C == 100) {
        const bool h = (sl < 9);
        int row = group;
        // main loop: 4 rows per group per iteration
        for (; row + 3 * ngroups < N; row += 4 * ngroups) {
            const int r0 = row, r1 = row + ngroups, r2 = row + 2 * ngroups, r3 = row + 3 * ngroups;
            const float4* p0 = (const float4*)(logits + (size_t)r0 * 100);
            const float4* p1 = (const float4*)(logits + (size_t)r1 * 100);
            const float4* p2 = (const float4*)(logits + (size_t)r2 * 100);
            const float4* p3 = (const float4*)(logits + (size_t)r3 * 100);
            // issue all independent loads up front
            float4 a0 = p0[sl], a1 = p1[sl], a2 = p2[sl], a3 = p3[sl];
            float4 b0, b1, b2, b3;
            if (h) { b0 = p0[16 + sl]; b1 = p1[16 + sl]; b2 = p2[16 + sl]; b3 = p3[16 + sl]; }
            else {
                b0 = b1 = b2 = b3 = make_float4(-INFINITY, -INFINITY, -INFINITY, -INFINITY);
            }
            int l0 = labels[r0], l1 = labels[r1], l2 = labels[r2], l3 = labels[r3];

            row_body(a0, b0, l0, sl, group16, s_bins);
            row_body(a1, b1, l1, sl, group16, s_bins);
            row_body(a2, b2, l2, sl, group16, s_bins);
            row_body(a3, b3, l3, sl, group16, s_bins);
        }
        // tail
        for (; row < N; row += ngroups) {
            const float4* p = (const float4*)(logits + (size_t)row * 100);
            float4 a = p[sl];
            float4 b = h ? p[16 + sl] : make_float4(-INFINITY, -INFINITY, -INFINITY, -INFINITY);
            int lab = labels[row];
            row_body(a, b, lab, sl, group16, s_bins);
        }
    } else {
        // generic fallback (not hit for this problem's shape)
        for (int row = group; row < N; row += ngroups) {
            const float* rp = logits + (size_t)row * C;
            float m = -INFINITY; int mi = C;
            for (int j = sl; j < C; j += 16) {
                float v = rp[j];
                if (v > m) { m = v; mi = j; }
            }
            #pragma unroll
            for (int off = 1; off < 16; off <<= 1) {
                float om = __shfl_xor(m, off);
                int   oi = __shfl_xor(mi, off);
                if (om > m || (om == m && oi < mi)) { m = om; mi = oi; }
            }
            float s = 0.f;
            for (int j = sl; j < C; j += 16) s += __expf(rp[j] - m);
            #pragma unroll
            for (int off = 1; off < 16; off <<= 1) s += __shfl_xor(s, off);
            if (sl == 0) {
                float conf = 1.0f / s;
                int bin = (int)ceilf(conf * (float)N_BINS) - 1;
                bin = min(max(bin, 0), N_BINS - 1);
                float acc = (mi == labels[row]) ? 1.0f : 0.0f;
                atomicAdd(&s_bins[bin], 1.0f);
                atomicAdd(&s_bins[N_BINS + bin], conf);
                atomicAdd(&s_bins[2 * N_BINS + bin], acc);
            }
        }
    }

    __syncthreads();
    if (tid < N_BINS) {
        atomicAdd(&ws[tid],              s_bins[tid]);
        atomicAdd(&ws[N_BINS + tid],     s_bins[N_BINS + tid]);
        atomicAdd(&ws[2 * N_BINS + tid], s_bins[2 * N_BINS + tid]);
    }
}

__global__ void ece_final(const float* __restrict__ ws, float* __restrict__ out, float invN) {
    if (threadIdx.x == 0 && blockIdx.x == 0) {
        float ece = 0.f;
        for (int b = 0; b < N_BINS; ++b) {
            float c = ws[b];
            if (c > 0.f) {
                float conf_m = ws[N_BINS + b] / c;
                float acc_m  = ws[2 * N_BINS + b] / c;
                ece += fabsf(conf_m - acc_m) * (c * invN);
            }
        }
        out[0] = ece;
    }
}

extern "C" void kernel_launch(void* const* d_in, const int* in_sizes, int n_in,
                              void* d_out, int out_size, void* d_ws, size_t ws_size,
                              hipStream_t stream) {
    const float* logits = (const float*)d_in[0];
    const int*   labels = (const int*)d_in[1];
    const int N = in_sizes[1];
    const int C = in_sizes[0] / N;
    float* ws = (float*)d_ws;

    hipMemsetAsync(ws, 0, 3 * N_BINS * sizeof(float), stream);

    const int threads = 256;
    const int blocks = 2048;   // full residency: 2048x256 = 524288 threads
    ece_main<<<blocks, threads, 0, stream>>>(logits, labels, ws, N, C);
    ece_final<<<1, 64, 0, stream>>>(ws, (float*)d_out, 1.0f / (float)N);
}